// Round 4
// baseline (683.605 us; speedup 1.0000x reference)
//
#include <hip/hip_runtime.h>
#include <hip/hip_bf16.h>
#include <stdint.h>

typedef unsigned short u16;
typedef __attribute__((ext_vector_type(8))) short short8;
typedef __attribute__((ext_vector_type(4))) float floatx4;

#define B_   512
#define D_   512
#define C_   100000

#define SCALE_  64.0f
#define COSM_   0.8775825618903728f
#define SINM_   0.479425538604203f
#define TH_     (-0.8775825618903728f)
#define MM_     0.2397127693021015f
#define EPS_    1e-7f
#define SHIFT_  89.6f

#define BM 256   // rows per block (M split in 2 across grid)
#define BN 64    // cols per block; each of 4 waves: 64 rows x 64 cols

__device__ inline float wave_reduce_sum(float v) {
    v += __shfl_xor(v, 1);
    v += __shfl_xor(v, 2);
    v += __shfl_xor(v, 4);
    v += __shfl_xor(v, 8);
    v += __shfl_xor(v, 16);
    v += __shfl_xor(v, 32);
    return v;
}

__device__ inline u16 f2bf(float x) {
    union { float f; uint32_t u; } v; v.f = x;
    uint32_t r = v.u + 0x7fffu + ((v.u >> 16) & 1u);  // RNE
    return (u16)(r >> 16);
}

// Fused: normalize embedding rows -> e_bf16, per-row phi (exact fp32 path),
// and zero-init rowsum.
__global__ __launch_bounds__(256) void norm_e_phi_kernel(
    const float* __restrict__ emb, const float* __restrict__ w_raw,
    const int* __restrict__ gt, u16* __restrict__ e_bf16,
    float* __restrict__ phi, float* __restrict__ rowsum) {
    if (threadIdx.x < 4) rowsum[blockIdx.x * 4 + threadIdx.x] = 0.0f;
    int wv = threadIdx.x >> 6;
    int lane = threadIdx.x & 63;
    int b = blockIdx.x * 4 + wv;
    const float4* rp = (const float4*)(emb + (long)b * D_);
    float4 f0 = rp[lane], f1 = rp[lane + 64];
    float sq = f0.x*f0.x + f0.y*f0.y + f0.z*f0.z + f0.w*f0.w
             + f1.x*f1.x + f1.y*f1.y + f1.z*f1.z + f1.w*f1.w;
    sq = wave_reduce_sum(sq);
    float rn = 1.0f / sqrtf(sq);
    f0.x *= rn; f0.y *= rn; f0.z *= rn; f0.w *= rn;
    f1.x *= rn; f1.y *= rn; f1.z *= rn; f1.w *= rn;
    uint2 p0, p1;
    p0.x = (uint32_t)f2bf(f0.x) | ((uint32_t)f2bf(f0.y) << 16);
    p0.y = (uint32_t)f2bf(f0.z) | ((uint32_t)f2bf(f0.w) << 16);
    p1.x = (uint32_t)f2bf(f1.x) | ((uint32_t)f2bf(f1.y) << 16);
    p1.y = (uint32_t)f2bf(f1.z) | ((uint32_t)f2bf(f1.w) << 16);
    uint2* ob = (uint2*)(e_bf16 + (long)b * D_);
    ob[lane] = p0;
    ob[lane + 64] = p1;

    int g = gt[b];
    const float4* wp = (const float4*)(w_raw + (long)g * D_);
    float4 w0 = wp[lane], w1 = wp[lane + 64];
    float dt = f0.x*w0.x + f0.y*w0.y + f0.z*w0.z + f0.w*w0.w
             + f1.x*w1.x + f1.y*w1.y + f1.z*w1.z + f1.w*w1.w;
    float wsq = w0.x*w0.x + w0.y*w0.y + w0.z*w0.z + w0.w*w0.w
              + w1.x*w1.x + w1.y*w1.y + w1.z*w1.z + w1.w*w1.w;
    dt = wave_reduce_sum(dt);
    wsq = wave_reduce_sum(wsq);
    if (lane == 0) {
        float pos = dt / sqrtf(wsq);
        pos = fminf(fmaxf(pos, -1.0f + EPS_), 1.0f - EPS_);
        float s2 = 1.0f - pos * pos;
        s2 = fminf(fmaxf(s2, EPS_), 1.0f - EPS_);
        float sin_t = sqrtf(s2);
        float ph = pos * COSM_ - sin_t * SINM_;
        ph = (pos > TH_) ? ph : (pos - MM_);
        phi[b] = ph;
    }
}

// pack 8 fp32 -> short8 of bf16 (RNE) and accumulate sum of squares
__device__ inline short8 cvt_pack8(const float4 v0, const float4 v1, float& sq) {
    union { __hip_bfloat162 b2[4]; short8 s; } u;
    u.b2[0] = __float22bfloat162_rn(float2{v0.x, v0.y});
    u.b2[1] = __float22bfloat162_rn(float2{v0.z, v0.w});
    u.b2[2] = __float22bfloat162_rn(float2{v1.x, v1.y});
    u.b2[3] = __float22bfloat162_rn(float2{v1.z, v1.w});
    sq += v0.x*v0.x + v0.y*v0.y + v0.z*v0.z + v0.w*v0.w
        + v1.x*v1.x + v1.y*v1.y + v1.z*v1.z + v1.w*v1.w;
    return u.s;
}

// Barrier-free fused GEMM+ArcFace. Block = 4 independent waves; wave wv
// computes rows [m0+wv*64, +64) x cols [c0, c0+64) x K=512. B is loaded
// global->register fp32 in MFMA B-layout (full-cacheline consumption per
// wave), converted to bf16 in-register; ||w||^2 accumulated on the fly.
// Depth-1 A/B register pipelines; NO __syncthreads in the K-loop, so loads
// stay in flight (fine-grained vmcnt) and waves slip freely.
__global__ __launch_bounds__(256, 3) void gemm_arcface_fused(
    const u16* __restrict__ a_g,     // e_bf16 [512][512]
    const float* __restrict__ w_g,   // raw weight fp32 [100000][512]
    const float* __restrict__ phi, const int* __restrict__ gt,
    float* __restrict__ rowsum) {
    __shared__ float phi_s[BM];
    __shared__ int gt_s[BM];

    int tid = threadIdx.x;
    int c0 = (blockIdx.x >> 1) * BN;
    int m0 = (blockIdx.x & 1) * BM;
    phi_s[tid] = phi[m0 + tid];
    gt_s[tid] = gt[m0 + tid];
    __syncthreads();   // the only block-wide barrier

    int wv = tid >> 6, lane = tid & 63;
    int low4 = lane & 15, quad = lane >> 4;

    // B pointers: lane covers col c0+ni*16+low4, k = kt*32 + quad*8 .. +8
    const float4* bp[4];
#pragma unroll
    for (int ni = 0; ni < 4; ni++) {
        long brow = min(c0 + ni * 16 + low4, C_ - 1);
        bp[ni] = (const float4*)(w_g + brow * (long)D_) + quad * 2;
    }
    // A pointer: row m0+wv*64+mi*16+low4, k = kt*32 + quad*8
    const u16* a_row = a_g + (long)(m0 + wv * 64 + low4) * D_ + quad * 8;

    floatx4 acc[4][4] = {};
    float sq4[4] = {0.0f, 0.0f, 0.0f, 0.0f};

    float4 bnx[4][2];
    short8 anx[4];
#pragma unroll
    for (int ni = 0; ni < 4; ni++) {
        bnx[ni][0] = bp[ni][0];
        bnx[ni][1] = bp[ni][1];
    }
#pragma unroll
    for (int mi = 0; mi < 4; mi++)
        anx[mi] = *(const short8*)(a_row + (long)mi * 16 * D_);

#pragma unroll
    for (int kt = 0; kt < 16; kt++) {
        float4 bt[4][2];
        short8 at[4];
#pragma unroll
        for (int ni = 0; ni < 4; ni++) { bt[ni][0] = bnx[ni][0]; bt[ni][1] = bnx[ni][1]; }
#pragma unroll
        for (int mi = 0; mi < 4; mi++) at[mi] = anx[mi];
        if (kt < 15) {
#pragma unroll
            for (int ni = 0; ni < 4; ni++) {
                bnx[ni][0] = bp[ni][(kt + 1) * 8];
                bnx[ni][1] = bp[ni][(kt + 1) * 8 + 1];
            }
#pragma unroll
            for (int mi = 0; mi < 4; mi++)
                anx[mi] = *(const short8*)(a_row + (long)mi * 16 * D_ + (kt + 1) * 32);
        }
        short8 bfr[4];
#pragma unroll
        for (int ni = 0; ni < 4; ni++)
            bfr[ni] = cvt_pack8(bt[ni][0], bt[ni][1], sq4[ni]);
#pragma unroll
        for (int mi = 0; mi < 4; mi++)
#pragma unroll
            for (int ni = 0; ni < 4; ni++)
                acc[mi][ni] = __builtin_amdgcn_mfma_f32_16x16x32_bf16(
                    at[mi], bfr[ni], acc[mi][ni], 0, 0, 0);
    }

    // per-column 1/||w||: lane holds k-slice {kt*32+quad*8..+8}; quads are
    // disjoint slices -> reduce across quad bits (lanes 16, 32)
    float rnorm[4];
#pragma unroll
    for (int ni = 0; ni < 4; ni++) {
        float s = sq4[ni];
        s += __shfl_xor(s, 16);
        s += __shfl_xor(s, 32);
        rnorm[ni] = 1.0f / sqrtf(s);
    }

    // epilogue: normalize, clip, reweight, gt-substitute, exp, row-reduce
#pragma unroll
    for (int mi = 0; mi < 4; mi++) {
#pragma unroll
        for (int r = 0; r < 4; r++) {
            int rl = wv * 64 + mi * 16 + quad * 4 + r;
            float ph = phi_s[rl];
            int g = gt_s[rl];
            float s = 0.0f;
#pragma unroll
            for (int ni = 0; ni < 4; ni++) {
                int c = c0 + ni * 16 + low4;
                float v = acc[mi][ni][r] * rnorm[ni];
                v = fminf(fmaxf(v, -1.0f + EPS_), 1.0f - EPS_);
                float logit = (v > ph) ? (1.2f * v + 0.2f) : v;
                logit *= SCALE_;
                if (c == g) logit = SCALE_ * ph;
                s += (c < C_) ? __expf(logit - SHIFT_) : 0.0f;
            }
            s += __shfl_xor(s, 1);
            s += __shfl_xor(s, 2);
            s += __shfl_xor(s, 4);
            s += __shfl_xor(s, 8);
            if (low4 == 0) atomicAdd(&rowsum[m0 + rl], s);
        }
    }
}

__global__ __launch_bounds__(256) void loss_kernel(
    const float* __restrict__ rowsum, const float* __restrict__ phi,
    float* __restrict__ out) {
    __shared__ float red[4];
    int tid = threadIdx.x;
    float s = 0.0f;
    for (int b = tid; b < B_; b += 256)
        s += logf(rowsum[b]) + SHIFT_ - SCALE_ * phi[b];
    s = wave_reduce_sum(s);
    int wv = tid >> 6, lane = tid & 63;
    if (lane == 0) red[wv] = s;
    __syncthreads();
    if (tid == 0) out[0] = (red[0] + red[1] + red[2] + red[3]) * (1.0f / B_);
}

extern "C" void kernel_launch(void* const* d_in, const int* in_sizes, int n_in,
                              void* d_out, int out_size, void* d_ws, size_t ws_size,
                              hipStream_t stream) {
    const float* emb = (const float*)d_in[0];   // [512][512] f32
    const float* wgt = (const float*)d_in[1];   // [100000][512] f32
    const int* gt = (const int*)d_in[2];        // [512] int32
    float* out = (float*)d_out;

    char* ws = (char*)d_ws;
    u16* e_bf16 = (u16*)(ws);                   //   524,288 B
    float* phi = (float*)(ws + 524288);         //     2,048 B
    float* rowsum = (float*)(ws + 526336);      //     2,048 B

    norm_e_phi_kernel<<<B_ / 4, 256, 0, stream>>>(emb, wgt, gt, e_bf16, phi, rowsum);
    int nc = (C_ + BN - 1) / BN;                // 1563 c-tiles
    gemm_arcface_fused<<<nc * 2, 256, 0, stream>>>(e_bf16, wgt, phi, gt, rowsum);
    loss_kernel<<<1, 256, 0, stream>>>(rowsum, phi, out);
}

// Round 5
// 469.631 us; speedup vs baseline: 1.4556x; 1.4556x over previous
//
#include <hip/hip_runtime.h>
#include <hip/hip_bf16.h>
#include <stdint.h>

typedef unsigned short u16;
typedef __attribute__((ext_vector_type(8))) short short8;
typedef __attribute__((ext_vector_type(4))) float floatx4;

#define B_   512
#define D_   512
#define C_   100000

#define SCALE_  64.0f
#define COSM_   0.8775825618903728f
#define SINM_   0.479425538604203f
#define TH_     (-0.8775825618903728f)
#define MM_     0.2397127693021015f
#define EPS_    1e-7f
#define SHIFT_  89.6f

#define BM 256   // rows per block (M split in 2 across grid)
#define BN 64    // cols per block
#define BK 128   // k per mega-step -> 4 barriers total

__device__ inline float wave_reduce_sum(float v) {
    v += __shfl_xor(v, 1);
    v += __shfl_xor(v, 2);
    v += __shfl_xor(v, 4);
    v += __shfl_xor(v, 8);
    v += __shfl_xor(v, 16);
    v += __shfl_xor(v, 32);
    return v;
}

__device__ inline u16 f2bf(float x) {
    union { float f; uint32_t u; } v; v.f = x;
    uint32_t r = v.u + 0x7fffu + ((v.u >> 16) & 1u);  // RNE
    return (u16)(r >> 16);
}

// Fused: normalize embedding rows -> e_bf16, per-row phi (exact fp32 path),
// and zero-init rowsum.
__global__ __launch_bounds__(256) void norm_e_phi_kernel(
    const float* __restrict__ emb, const float* __restrict__ w_raw,
    const int* __restrict__ gt, u16* __restrict__ e_bf16,
    float* __restrict__ phi, float* __restrict__ rowsum) {
    if (threadIdx.x < 4) rowsum[blockIdx.x * 4 + threadIdx.x] = 0.0f;
    int wv = threadIdx.x >> 6;
    int lane = threadIdx.x & 63;
    int b = blockIdx.x * 4 + wv;
    const float4* rp = (const float4*)(emb + (long)b * D_);
    float4 f0 = rp[lane], f1 = rp[lane + 64];
    float sq = f0.x*f0.x + f0.y*f0.y + f0.z*f0.z + f0.w*f0.w
             + f1.x*f1.x + f1.y*f1.y + f1.z*f1.z + f1.w*f1.w;
    sq = wave_reduce_sum(sq);
    float rn = 1.0f / sqrtf(sq);
    f0.x *= rn; f0.y *= rn; f0.z *= rn; f0.w *= rn;
    f1.x *= rn; f1.y *= rn; f1.z *= rn; f1.w *= rn;
    uint2 p0, p1;
    p0.x = (uint32_t)f2bf(f0.x) | ((uint32_t)f2bf(f0.y) << 16);
    p0.y = (uint32_t)f2bf(f0.z) | ((uint32_t)f2bf(f0.w) << 16);
    p1.x = (uint32_t)f2bf(f1.x) | ((uint32_t)f2bf(f1.y) << 16);
    p1.y = (uint32_t)f2bf(f1.z) | ((uint32_t)f2bf(f1.w) << 16);
    uint2* ob = (uint2*)(e_bf16 + (long)b * D_);
    ob[lane] = p0;
    ob[lane + 64] = p1;

    int g = gt[b];
    const float4* wp = (const float4*)(w_raw + (long)g * D_);
    float4 w0 = wp[lane], w1 = wp[lane + 64];
    float dt = f0.x*w0.x + f0.y*w0.y + f0.z*w0.z + f0.w*w0.w
             + f1.x*w1.x + f1.y*w1.y + f1.z*w1.z + f1.w*w1.w;
    float wsq = w0.x*w0.x + w0.y*w0.y + w0.z*w0.z + w0.w*w0.w
              + w1.x*w1.x + w1.y*w1.y + w1.z*w1.z + w1.w*w1.w;
    dt = wave_reduce_sum(dt);
    wsq = wave_reduce_sum(wsq);
    if (lane == 0) {
        float pos = dt / sqrtf(wsq);
        pos = fminf(fmaxf(pos, -1.0f + EPS_), 1.0f - EPS_);
        float s2 = 1.0f - pos * pos;
        s2 = fminf(fmaxf(s2, EPS_), 1.0f - EPS_);
        float sin_t = sqrtf(s2);
        float ph = pos * COSM_ - sin_t * SINM_;
        ph = (pos > TH_) ? ph : (pos - MM_);
        phi[b] = ph;
    }
}

__device__ inline void cvt_store(const float4& v0, const float4& v1,
                                 u16* dst, float& sq) {
    union { u16 h[8]; uint4 q; } u;
    u.h[0] = f2bf(v0.x); u.h[1] = f2bf(v0.y);
    u.h[2] = f2bf(v0.z); u.h[3] = f2bf(v0.w);
    u.h[4] = f2bf(v1.x); u.h[5] = f2bf(v1.y);
    u.h[6] = f2bf(v1.z); u.h[7] = f2bf(v1.w);
    *(uint4*)dst = u.q;
    sq += v0.x*v0.x + v0.y*v0.y + v0.z*v0.z + v0.w*v0.w
        + v1.x*v1.x + v1.y*v1.y + v1.z*v1.z + v1.w*v1.w;
}

// Fused GEMM+ArcFace, BK=128 double-buffered LDS B-staging (4 barriers).
// Loads for mega-step s+1 issue at the top of step s; 64 MFMAs/wave cover
// the ~900-cycle HBM latency, so the pre-barrier vmcnt(0) drain is cheap.
// B tile stored as 4 sub-tiles [kg][64 rows][32 k] with the R3-proven
// XOR-slot swizzle (0 bank conflicts). A fragments straight from L1/L2.
__global__ __launch_bounds__(256, 3) void gemm_arcface_fused(
    const u16* __restrict__ a_g,     // e_bf16 [512][512]
    const float* __restrict__ w_g,   // raw weight fp32 [100000][512]
    const float* __restrict__ phi, const int* __restrict__ gt,
    float* __restrict__ rowsum) {
    __shared__ __align__(16) u16 b_tile[2][4][64 * 32];  // 2 x 16 KB
    __shared__ float phi_s[BM];
    __shared__ int gt_s[BM];
    __shared__ float rnorm_s[BN];

    int tid = threadIdx.x;
    int c0 = (blockIdx.x >> 1) * BN;
    int m0 = (blockIdx.x & 1) * BM;
    phi_s[tid] = phi[m0 + tid];
    gt_s[tid] = gt[m0 + tid];

    // Staging: thread t owns row rb = t>>2, k-group g = t&3 (32 k values).
    // Within the group, LDS slot s holds global k-quad kq = s ^ ((rb>>1)&3).
    int rb = tid >> 2;
    int g_ = tid & 3;
    int swz = (rb >> 1) & 3;
    long brow_g = min(c0 + rb, C_ - 1);
    const float4* b_src = (const float4*)(w_g + brow_g * (long)D_) + g_ * 8;
    u16* b_dst[2];
    b_dst[0] = &b_tile[0][g_][rb * 32];
    b_dst[1] = &b_tile[1][g_][rb * 32];

    int wv = tid >> 6, lane = tid & 63;
    int low4 = lane & 15, quad = lane >> 4;
    int lslot = quad ^ ((low4 >> 1) & 3);
    const u16* a_row = a_g + (long)(m0 + wv * 64 + low4) * D_ + quad * 8;
    int bf_off = low4 * 32 + lslot * 8;

    floatx4 acc[4][4] = {};
    float sq = 0.0f;

    // prologue: stage mega-step 0 into buffer 0
    {
        float4 Lv[4][2];
#pragma unroll
        for (int s = 0; s < 4; s++) {
            int kq = s ^ swz;
            Lv[s][0] = b_src[kq * 2];
            Lv[s][1] = b_src[kq * 2 + 1];
        }
#pragma unroll
        for (int s = 0; s < 4; s++)
            cvt_store(Lv[s][0], Lv[s][1], b_dst[0] + s * 8, sq);
    }
    __syncthreads();

#pragma unroll
    for (int st = 0; st < 4; st++) {
        int p = st & 1;
        float4 Lv[4][2];
        if (st < 3) {
#pragma unroll
            for (int s = 0; s < 4; s++) {
                int kq = s ^ swz;
                Lv[s][0] = b_src[(st + 1) * 32 + kq * 2];
                Lv[s][1] = b_src[(st + 1) * 32 + kq * 2 + 1];
            }
        }
#pragma unroll
        for (int kg = 0; kg < 4; kg++) {
            short8 at[4], bf[4];
#pragma unroll
            for (int mi = 0; mi < 4; mi++)
                at[mi] = *(const short8*)(a_row + (long)mi * 16 * D_
                                          + (st * 4 + kg) * 32);
#pragma unroll
            for (int ni = 0; ni < 4; ni++)
                bf[ni] = *(const short8*)(&b_tile[p][kg][ni * 16 * 32 + bf_off]);
#pragma unroll
            for (int mi = 0; mi < 4; mi++)
#pragma unroll
                for (int ni = 0; ni < 4; ni++)
                    acc[mi][ni] = __builtin_amdgcn_mfma_f32_16x16x32_bf16(
                        at[mi], bf[ni], acc[mi][ni], 0, 0, 0);
        }
        if (st < 3) {
#pragma unroll
            for (int s = 0; s < 4; s++)
                cvt_store(Lv[s][0], Lv[s][1], b_dst[1 - p] + s * 8, sq);
        }
        __syncthreads();
    }

    // per-row ||w||^2: the 4 threads (rb, g=0..3) hold disjoint k-groups
    sq += __shfl_xor(sq, 1);
    sq += __shfl_xor(sq, 2);
    if (g_ == 0) rnorm_s[rb] = 1.0f / sqrtf(sq);
    __syncthreads();

    // epilogue: normalize, clip, reweight, gt-substitute, exp, row-reduce
#pragma unroll
    for (int mi = 0; mi < 4; mi++) {
#pragma unroll
        for (int r = 0; r < 4; r++) {
            int rl = wv * 64 + mi * 16 + quad * 4 + r;
            float ph = phi_s[rl];
            int g = gt_s[rl];
            float s = 0.0f;
#pragma unroll
            for (int ni = 0; ni < 4; ni++) {
                int cl = ni * 16 + low4;
                int c = c0 + cl;
                float v = acc[mi][ni][r] * rnorm_s[cl];
                v = fminf(fmaxf(v, -1.0f + EPS_), 1.0f - EPS_);
                float logit = (v > ph) ? (1.2f * v + 0.2f) : v;
                logit *= SCALE_;
                if (c == g) logit = SCALE_ * ph;
                s += (c < C_) ? __expf(logit - SHIFT_) : 0.0f;
            }
            s += __shfl_xor(s, 1);
            s += __shfl_xor(s, 2);
            s += __shfl_xor(s, 4);
            s += __shfl_xor(s, 8);
            if (low4 == 0) atomicAdd(&rowsum[m0 + rl], s);
        }
    }
}

__global__ __launch_bounds__(256) void loss_kernel(
    const float* __restrict__ rowsum, const float* __restrict__ phi,
    float* __restrict__ out) {
    __shared__ float red[4];
    int tid = threadIdx.x;
    float s = 0.0f;
    for (int b = tid; b < B_; b += 256)
        s += logf(rowsum[b]) + SHIFT_ - SCALE_ * phi[b];
    s = wave_reduce_sum(s);
    int wv = tid >> 6, lane = tid & 63;
    if (lane == 0) red[wv] = s;
    __syncthreads();
    if (tid == 0) out[0] = (red[0] + red[1] + red[2] + red[3]) * (1.0f / B_);
}

extern "C" void kernel_launch(void* const* d_in, const int* in_sizes, int n_in,
                              void* d_out, int out_size, void* d_ws, size_t ws_size,
                              hipStream_t stream) {
    const float* emb = (const float*)d_in[0];   // [512][512] f32
    const float* wgt = (const float*)d_in[1];   // [100000][512] f32
    const int* gt = (const int*)d_in[2];        // [512] int32
    float* out = (float*)d_out;

    char* ws = (char*)d_ws;
    u16* e_bf16 = (u16*)(ws);                   //   524,288 B
    float* phi = (float*)(ws + 524288);         //     2,048 B
    float* rowsum = (float*)(ws + 526336);      //     2,048 B

    norm_e_phi_kernel<<<B_ / 4, 256, 0, stream>>>(emb, wgt, gt, e_bf16, phi, rowsum);
    int nc = (C_ + BN - 1) / BN;                // 1563 c-tiles
    gemm_arcface_fused<<<nc * 2, 256, 0, stream>>>(e_bf16, wgt, phi, gt, rowsum);
    loss_kernel<<<1, 256, 0, stream>>>(rowsum, phi, out);
}